// Round 17
// baseline (88.137 us; speedup 1.0000x reference)
//
#include <hip/hip_runtime.h>

#define B 8
#define C 256
#define L 2048
#define CQK 32
#define NT (L / 32)          // 64 j-tiles per block (full row range)
#define SM_SHIFT2 28.8539008f   // 20 * log2(e); Q pre-scaled by log2(e)

typedef unsigned short u16;
typedef __attribute__((ext_vector_type(8))) short bf8;   // 8 bf16 = 4 VGPR
typedef __attribute__((ext_vector_type(4))) float f4;    // mfma C/D

__device__ __forceinline__ u16 f2bf(float f) {
    union { float f; unsigned u; } v; v.f = f;
    unsigned r = v.u + 0x7FFFu + ((v.u >> 16) & 1u);   // RNE
    return (u16)(r >> 16);
}
__device__ __forceinline__ unsigned cvtpk(float lo, float hi) {
    unsigned r;
    asm("v_cvt_pk_bf16_f32 %0, %1, %2" : "=v"(r) : "v"(lo), "v"(hi));
    return r;
}
__device__ __forceinline__ float ex2(float x) {   // 2^x
    float r;
    asm("v_exp_f32 %0, %1" : "=v"(r) : "v"(x));
    return r;
}

__device__ __forceinline__ void gld16(const u16* gp, u16* lp) {
    auto* g1 = (const __attribute__((address_space(1))) u16*)gp;
    auto* l3 = (__attribute__((address_space(3))) u16*)lp;
    __builtin_amdgcn_global_load_lds(g1, l3, 16, 0, 0);
}
__device__ __forceinline__ void wait_vm0() {
    asm volatile("s_waitcnt vmcnt(0)" ::: "memory");
    __builtin_amdgcn_sched_barrier(0);
}
__device__ __forceinline__ void wait_vm1() {
    asm volatile("s_waitcnt vmcnt(1)" ::: "memory");
    __builtin_amdgcn_sched_barrier(0);
}
__device__ __forceinline__ void wait_lgkm0() {
    asm volatile("s_waitcnt lgkmcnt(0)" ::: "memory");
    __builtin_amdgcn_sched_barrier(0);
}
__device__ __forceinline__ void bar() {
    __builtin_amdgcn_sched_barrier(0);
    __builtin_amdgcn_s_barrier();
    __builtin_amdgcn_sched_barrier(0);
}

// ---------------------------------------------------------------------------
// wconv: W{q,k,v} fp32 -> Wall[320][256] bf16 ; biases -> ball[320] fp32
// ---------------------------------------------------------------------------
__global__ __launch_bounds__(256) void wconv(
    const float* __restrict__ Wq, const float* __restrict__ bq,
    const float* __restrict__ Wk, const float* __restrict__ bk,
    const float* __restrict__ Wv, const float* __restrict__ bv,
    u16* __restrict__ Wall, float* __restrict__ ball)
{
    const int idx = (blockIdx.x * 256 + threadIdx.x) * 4;
    const int row = idx >> 8, c = idx & 255;
    const float* s;
    if (row < 32)      s = Wq + row * C + c;
    else if (row < 64) s = Wk + (row - 32) * C + c;
    else               s = Wv + (row - 64) * C + c;
    const float4 v = *(const float4*)s;
    uint2 o;
    o.x = f2bf(v.x) | ((unsigned)f2bf(v.y) << 16);
    o.y = f2bf(v.z) | ((unsigned)f2bf(v.w) << 16);
    *(uint2*)(Wall + idx) = o;
    if (blockIdx.x == 0) {
        for (int i = threadIdx.x; i < 320; i += 256)
            ball[i] = (i < 32) ? bq[i] : (i < 64) ? bk[i - 32] : bv[i - 64];
    }
}

// ---------------------------------------------------------------------------
// xconv: x[b][c][l] fp32 -> xt[b][l][c] bf16 (LDS transpose)
// ---------------------------------------------------------------------------
__global__ __launch_bounds__(256) void xconv(const float* __restrict__ x,
                                             u16* __restrict__ xt)
{
    __shared__ float tile[64][65];
    const int b = blockIdx.z, c0 = blockIdx.y * 64, l0 = blockIdx.x * 64;
    const int t = threadIdx.x;
    const int ln = t & 63, w = t >> 6;
#pragma unroll
    for (int i = 0; i < 16; i++) {
        const int c = w * 16 + i;
        tile[c][ln] = x[((size_t)(b * C + c0 + c)) * L + l0 + ln];
    }
    __syncthreads();
    const int lrow = t >> 2, q = t & 3;
    unsigned o[8];
#pragma unroll
    for (int jj = 0; jj < 8; jj++) {
        const float a0 = tile[q * 16 + jj * 2][lrow];
        const float a1 = tile[q * 16 + jj * 2 + 1][lrow];
        o[jj] = f2bf(a0) | ((unsigned)f2bf(a1) << 16);
    }
    u16* dst = xt + ((size_t)(b * L + l0 + lrow)) * 256 + c0 + q * 16;
    *(uint4*)(dst)     = make_uint4(o[0], o[1], o[2], o[3]);
    *(uint4*)(dst + 8) = make_uint4(o[4], o[5], o[6], o[7]);
}

// ---------------------------------------------------------------------------
// proj: [320x256] x [256 x L] MFMA GEMM per batch. l-tile = 32 (grid 512).
// Q rows pre-scaled by log2(e) so attn can use raw v_exp_f32 (2^x).
// ---------------------------------------------------------------------------
__global__ __launch_bounds__(256) void proj(
    const u16* __restrict__ xt, const u16* __restrict__ Wall,
    const float* __restrict__ ball, u16* __restrict__ qt,
    u16* __restrict__ kt, u16* __restrict__ vv)
{
    __shared__ u16 xlds[32 * 256];   // 16 KB
    const int b = blockIdx.y, l0 = blockIdx.x * 32;
    const int t = threadIdx.x, w = t >> 6, ln = t & 63;
    const int lc = ln & 15, g = ln >> 4;

#pragma unroll
    for (int mm = 0; mm < 4; mm++) {
        const int cg = t + mm * 256;           // chunk 0..1023
        const int lrow = cg >> 5, phys = cg & 31;
        const int logical = (phys & 24) | ((phys & 7) ^ (lrow & 7));
        gld16(xt + ((size_t)(b * L + l0 + lrow)) * 256 + logical * 8,
              xlds + (size_t)(w * 64 + mm * 256) * 8);
    }
    __syncthreads();

    f4 acc[5][2];
#pragma unroll
    for (int rt = 0; rt < 5; rt++) {
        const int row0 = (w * 5 + rt) * 16 + g * 4;
        const float4 bi = *(const float4*)(ball + row0);
#pragma unroll
        for (int ct = 0; ct < 2; ct++) {
            acc[rt][ct].x = bi.x; acc[rt][ct].y = bi.y;
            acc[rt][ct].z = bi.z; acc[rt][ct].w = bi.w;
        }
    }

#pragma unroll
    for (int k = 0; k < 8; k++) {
        bf8 bfr[2];
#pragma unroll
        for (int ct = 0; ct < 2; ct++) {
            const int lrow = ct * 16 + lc;
            const int lchunk = k * 4 + g;
            const int phys = (lchunk & 24) | ((lchunk & 7) ^ (lrow & 7));
            bfr[ct] = *(const bf8*)(xlds + (size_t)lrow * 256 + phys * 8);
        }
#pragma unroll
        for (int rt = 0; rt < 5; rt++) {
            const bf8 af = *(const bf8*)(Wall +
                (size_t)((w * 5 + rt) * 16 + lc) * 256 + k * 32 + g * 8);
#pragma unroll
            for (int ct = 0; ct < 2; ct++)
                acc[rt][ct] = __builtin_amdgcn_mfma_f32_16x16x32_bf16(
                    af, bfr[ct], acc[rt][ct], 0, 0, 0);
        }
    }

    const float Q_SCALE = 1.44269504f;   // log2(e)
#pragma unroll
    for (int rt = 0; rt < 5; rt++) {
        const int rg = w * 5 + rt;
        const int row0 = rg * 16 + g * 4;
#pragma unroll
        for (int ct = 0; ct < 2; ct++) {
            const int l = l0 + ct * 16 + lc;
            const f4 a = acc[rt][ct];
            if (rg < 2) {
                uint2 o;
                o.x = f2bf(a.x * Q_SCALE) | ((unsigned)f2bf(a.y * Q_SCALE) << 16);
                o.y = f2bf(a.z * Q_SCALE) | ((unsigned)f2bf(a.w * Q_SCALE) << 16);
                *(uint2*)(qt + ((size_t)(b * L + l)) * 32 + row0) = o;
            } else if (rg < 4) {
                uint2 o;
                o.x = f2bf(a.x) | ((unsigned)f2bf(a.y) << 16);
                o.y = f2bf(a.z) | ((unsigned)f2bf(a.w) << 16);
                *(uint2*)(kt + ((size_t)(b * L + l)) * 32 + (row0 - 32)) = o;
            } else {
                const int c = row0 - 64;
                vv[((size_t)(b * C + c + 0)) * L + l] = f2bf(a.x);
                vv[((size_t)(b * C + c + 1)) * L + l] = f2bf(a.y);
                vv[((size_t)(b * C + c + 2)) * L + l] = f2bf(a.z);
                vv[((size_t)(b * C + c + 3)) * L + l] = f2bf(a.w);
            }
        }
    }
}

// ---------------------------------------------------------------------------
// attn: FUSED full-row flash attention, 16-wave (1024-thr) blocks, grid 256
// = exactly 1 block/CU (no tail), 4 waves/SIMD. No split-j: no po/plsum/
// combine. Wave w owns c-rows [16w,16w+16) for PV (acc[4][1] = 16 VGPR);
// waves 0-3 additionally own softmax of i-tile w (one QK wave per SIMD).
// One barrier per 32-j tile (R16 ps-dbuf hazard argument). V wave-private
// single-gld16 dbuf with 3-term XOR swizzle (conflict-free, re-enumerated
// at 16 rows). K via asm loads, prefetched 1 tile; counted vmcnt(1) drains
// only tile-old loads. Epilogue: out = gamma*O/lsum + x direct (float4
// stores fully cover 64B sectors). XCD locality: b = fid&7 -> all 32 blocks
// of batch b on one XCD.
// ---------------------------------------------------------------------------
__global__ __launch_bounds__(1024, 4) void attn(
    const u16* __restrict__ qt, const u16* __restrict__ kt,
    const u16* __restrict__ vv, const float* __restrict__ x,
    const float* __restrict__ gamma_p, float* __restrict__ out)
{
    __shared__ u16 vsw[16][2][512];   // 32 KB: per-wave dbuf (16 rows x 32 j)
    __shared__ u16 ps[2][64][40];     // 10 KB: double-buffered P, 80B rows
    __shared__ float fl[64];

    const int fid = blockIdx.x;
    const int b = fid & 7, bx = fid >> 3;          // batch = XCD id
    const int t = threadIdx.x, w = t >> 6, ln = t & 63;
    const int lc = ln & 15, g = ln >> 4;
    const int i0 = bx * 64;
    const int wc0 = w * 16;

    // V staging source: lane ln -> row r0 = ln>>2 (0..15), slot s0 = ln&3
    // holds j-chunk s0 ^ (r0&3) ^ ((r0>>2)&3)  (R15/16-verified swizzle)
    const int r0 = ln >> 2, s0 = ln & 3;
    const int gch = s0 ^ (r0 & 3) ^ ((r0 >> 2) & 3);
    const u16* vsrc = vv + ((size_t)(b * C + wc0 + r0)) * L + gch * 8;

    f4 acc[4];
    const f4 fz = {0.f, 0.f, 0.f, 0.f};
#pragma unroll
    for (int it = 0; it < 4; it++) acc[it] = fz;
    float lsum = 0.f;

    bf8 qf = {}, kf0 = {}, kf1 = {};
    const u16* kb = kt;
    if (w < 4) {
        qf = *(const bf8*)(qt + ((size_t)(b * L + i0 + w * 16 + lc)) * 32 + g * 8);
        kb = kt + ((size_t)(b * L + lc)) * 32 + g * 8;
    }

    auto stage = [&](int buf, int jt) {
        gld16(vsrc + jt * 32, &vsw[w][buf][0]);   // 1 instr: 64 chunks
    };
    auto kload = [&](int jt) {             // in-place asm loads (R11-proven)
        asm volatile("global_load_dwordx4 %0, %1, off"
                     : "=&v"(kf0) : "v"(kb + (size_t)(jt * 32) * 32) : "memory");
        asm volatile("global_load_dwordx4 %0, %1, off"
                     : "=&v"(kf1) : "v"(kb + (size_t)(jt * 32 + 16) * 32) : "memory");
    };

    stage(0, 0);
    if (w < 4) kload(0);
    int cur = 0;

    // PV read offset (u16): chunk = lc*4 + (g ^ (lc&3) ^ ((lc>>2)&3))
    const int sread = (g ^ (lc & 3) ^ ((lc >> 2) & 3)) * 8;

#pragma unroll 1
    for (int jt = 0; jt < NT; jt++) {
        if (jt + 1 < NT) {
            stage(cur ^ 1, jt + 1);        // prefetch next V (newest, 1 instr)
            wait_vm1();                    // drain tile-old stage(jt)+kload(jt)
        } else {
            wait_vm0();                    // tail: drain everything
        }

        if (w < 4) {
            // ---- QK: S^T[j][i-tile w] ----
            const f4 sA = __builtin_amdgcn_mfma_f32_16x16x32_bf16(kf0, qf, fz, 0, 0, 0);
            const f4 sB = __builtin_amdgcn_mfma_f32_16x16x32_bf16(kf1, qf, fz, 0, 0, 0);
            if (jt + 1 < NT) kload(jt + 1);   // K prefetch, stays in flight
            // ---- shifted softmax numerators (2^x; Q pre-scaled) ----
            const float p0 = ex2(sA.x - SM_SHIFT2);
            const float p1 = ex2(sA.y - SM_SHIFT2);
            const float p2 = ex2(sA.z - SM_SHIFT2);
            const float p3 = ex2(sA.w - SM_SHIFT2);
            const float p4 = ex2(sB.x - SM_SHIFT2);
            const float p5 = ex2(sB.y - SM_SHIFT2);
            const float p6 = ex2(sB.z - SM_SHIFT2);
            const float p7 = ex2(sB.w - SM_SHIFT2);
            uint2 oa, ob;
            oa.x = cvtpk(p0, p1); oa.y = cvtpk(p2, p3);
            ob.x = cvtpk(p4, p5); ob.y = cvtpk(p6, p7);
            *(uint2*)(&ps[jt & 1][w * 16 + lc][g * 4]) = oa;
            *(uint2*)(&ps[jt & 1][w * 16 + lc][16 + g * 4]) = ob;
            float psum = ((p0 + p1) + (p2 + p3)) + ((p4 + p5) + (p6 + p7));
            psum += __shfl_xor(psum, 16);
            psum += __shfl_xor(psum, 32);
            lsum += psum;
        }

        wait_lgkm0();               // ps writes + prior PV reads drained
        bar();                      // the ONLY barrier: P(jt) published

        // ---- PV: own 16 c-rows, conflict-free b128 reads ----
        const u16* rb = &vsw[w][cur][0];
        __builtin_amdgcn_s_setprio(1);
        {
            const bf8 vfr = *(const bf8*)(rb + lc * 32 + sread);
#pragma unroll
            for (int it = 0; it < 4; it++) {
                const bf8 paf = *(const bf8*)(&ps[jt & 1][it * 16 + lc][0] + g * 8);
                acc[it] = __builtin_amdgcn_mfma_f32_16x16x32_bf16(
                    paf, vfr, acc[it], 0, 0, 0);
            }
        }
        __builtin_amdgcn_s_setprio(0);
        cur ^= 1;
    }

    // ---- fused epilogue: out = gamma * O / lsum + x ----
    if (w < 4) fl[w * 16 + lc] = 1.0f / lsum;     // all g write same value
    __syncthreads();
    const float gmm = gamma_p[0];
    const int c = wc0 + lc;
#pragma unroll
    for (int it = 0; it < 4; it++) {
        const float4 iv = *(const float4*)&fl[it * 16 + g * 4];
        const size_t adr = ((size_t)(b * C + c)) * L + i0 + it * 16 + g * 4;
        const float4 xv = *(const float4*)(x + adr);
        float4 o;
        o.x = gmm * acc[it].x * iv.x + xv.x;
        o.y = gmm * acc[it].y * iv.y + xv.y;
        o.z = gmm * acc[it].z * iv.z + xv.z;
        o.w = gmm * acc[it].w * iv.w + xv.w;
        *(float4*)(out + adr) = o;
    }
}

extern "C" void kernel_launch(void* const* d_in, const int* in_sizes, int n_in,
                              void* d_out, int out_size, void* d_ws, size_t ws_size,
                              hipStream_t stream) {
    const float* x  = (const float*)d_in[0];
    const float* Wq = (const float*)d_in[1];
    const float* bq = (const float*)d_in[2];
    const float* Wk = (const float*)d_in[3];
    const float* bk = (const float*)d_in[4];
    const float* Wv = (const float*)d_in[5];
    const float* bv = (const float*)d_in[6];
    const float* gm = (const float*)d_in[7];
    float* out = (float*)d_out;

    // ws layout (u16 units)
    u16* vvp  = (u16*)d_ws;                          // B*C*L      (8 MB)
    u16* qtp  = vvp + (size_t)B * C * L;             // B*L*CQK    (1 MB)
    u16* ktp  = qtp + (size_t)B * L * CQK;           // B*L*CQK    (1 MB)
    u16* Wall = ktp + (size_t)B * L * CQK;           // 320*256    (160 KB)
    float* ball = (float*)(Wall + 320 * 256);        // 320 fp32
    u16* xt   = Wall + 320 * 256 + 640;              // B*L*C      (8 MB)

    wconv<<<80, 256, 0, stream>>>(Wq, bq, Wk, bk, Wv, bv, Wall, ball);
    xconv<<<dim3(L / 64, C / 64, B), 256, 0, stream>>>(x, xt);
    proj<<<dim3(L / 32, B), 256, 0, stream>>>(xt, Wall, ball, qtp, ktp, vvp);
    attn<<<256, 1024, 0, stream>>>(qtp, ktp, vvp, x, gm, out);
}

// Round 18
// 67.809 us; speedup vs baseline: 1.2998x; 1.2998x over previous
//
#include <hip/hip_runtime.h>

#define B 8
#define C 256
#define L 2048
#define CQK 32
#define SSEG 4
#define JSEG (L / SSEG)      // 512
#define NT (JSEG / 32)       // 16 j-tiles per block
#define SM_SHIFT2 28.8539008f   // 20 * log2(e); Q pre-scaled by log2(e)

typedef unsigned short u16;
typedef __attribute__((ext_vector_type(8))) short bf8;   // 8 bf16 = 4 VGPR
typedef __attribute__((ext_vector_type(4))) float f4;    // mfma C/D

__device__ __forceinline__ u16 f2bf(float f) {
    union { float f; unsigned u; } v; v.f = f;
    unsigned r = v.u + 0x7FFFu + ((v.u >> 16) & 1u);   // RNE
    return (u16)(r >> 16);
}
__device__ __forceinline__ float bfl(unsigned u) {
    union { unsigned u; float f; } v; v.u = u << 16; return v.f;
}
__device__ __forceinline__ float bfh(unsigned u) {
    union { unsigned u; float f; } v; v.u = u & 0xFFFF0000u; return v.f;
}
__device__ __forceinline__ float ex2(float x) {   // 2^x
    float r;
    asm("v_exp_f32 %0, %1" : "=v"(r) : "v"(x));
    return r;
}

__device__ __forceinline__ void gld16(const u16* gp, u16* lp) {
    auto* g1 = (const __attribute__((address_space(1))) u16*)gp;
    auto* l3 = (__attribute__((address_space(3))) u16*)lp;
    __builtin_amdgcn_global_load_lds(g1, l3, 16, 0, 0);
}
__device__ __forceinline__ void wait_vm0() {
    asm volatile("s_waitcnt vmcnt(0)" ::: "memory");
    __builtin_amdgcn_sched_barrier(0);
}
__device__ __forceinline__ void wait_lgkm0() {
    asm volatile("s_waitcnt lgkmcnt(0)" ::: "memory");
    __builtin_amdgcn_sched_barrier(0);
}
__device__ __forceinline__ void bar() {
    __builtin_amdgcn_sched_barrier(0);
    __builtin_amdgcn_s_barrier();
    __builtin_amdgcn_sched_barrier(0);
}

// ---------------------------------------------------------------------------
// prep: merged xconv (blocks 0..1023) + wconv (blocks 1024..1103).
// xconv: x[b][c][l] fp32 -> xt[b][l][c] bf16 (LDS transpose).
// wconv: W{q,k,v} fp32 -> Wall[320][256] bf16 ; biases -> ball[320] fp32.
// ---------------------------------------------------------------------------
__global__ __launch_bounds__(256) void prep(
    const float* __restrict__ x, u16* __restrict__ xt,
    const float* __restrict__ Wq, const float* __restrict__ bq,
    const float* __restrict__ Wk, const float* __restrict__ bk,
    const float* __restrict__ Wv, const float* __restrict__ bv,
    u16* __restrict__ Wall, float* __restrict__ ball)
{
    __shared__ float tile[64][65];
    const int id = blockIdx.x;
    const int t = threadIdx.x;
    if (id < 1024) {
        const int l0 = (id & 31) * 64, c0 = ((id >> 5) & 3) * 64, b = id >> 7;
        const int ln = t & 63, w = t >> 6;
#pragma unroll
        for (int i = 0; i < 16; i++) {
            const int c = w * 16 + i;
            tile[c][ln] = x[((size_t)(b * C + c0 + c)) * L + l0 + ln];
        }
        __syncthreads();
        const int lrow = t >> 2, q = t & 3;
        unsigned o[8];
#pragma unroll
        for (int jj = 0; jj < 8; jj++) {
            const float a0 = tile[q * 16 + jj * 2][lrow];
            const float a1 = tile[q * 16 + jj * 2 + 1][lrow];
            o[jj] = f2bf(a0) | ((unsigned)f2bf(a1) << 16);
        }
        u16* dst = xt + ((size_t)(b * L + l0 + lrow)) * 256 + c0 + q * 16;
        *(uint4*)(dst)     = make_uint4(o[0], o[1], o[2], o[3]);
        *(uint4*)(dst + 8) = make_uint4(o[4], o[5], o[6], o[7]);
    } else {
        const int id2 = id - 1024;
        const int idx = (id2 * 256 + t) * 4;
        const int row = idx >> 8, c = idx & 255;
        const float* s;
        if (row < 32)      s = Wq + row * C + c;
        else if (row < 64) s = Wk + (row - 32) * C + c;
        else               s = Wv + (row - 64) * C + c;
        const float4 v = *(const float4*)s;
        uint2 o;
        o.x = f2bf(v.x) | ((unsigned)f2bf(v.y) << 16);
        o.y = f2bf(v.z) | ((unsigned)f2bf(v.w) << 16);
        *(uint2*)(Wall + idx) = o;
        if (id2 == 0) {
            for (int i = t; i < 320; i += 256)
                ball[i] = (i < 32) ? bq[i] : (i < 64) ? bk[i - 32] : bv[i - 64];
        }
    }
}

// ---------------------------------------------------------------------------
// proj: [320x256] x [256 x L] MFMA GEMM per batch. l-tile = 32 (grid 512).
// Q rows pre-scaled by log2(e) so attn can use raw v_exp_f32 (2^x).
// ---------------------------------------------------------------------------
__global__ __launch_bounds__(256) void proj(
    const u16* __restrict__ xt, const u16* __restrict__ Wall,
    const float* __restrict__ ball, u16* __restrict__ qt,
    u16* __restrict__ kt, u16* __restrict__ vv)
{
    __shared__ u16 xlds[32 * 256];   // 16 KB
    const int b = blockIdx.y, l0 = blockIdx.x * 32;
    const int t = threadIdx.x, w = t >> 6, ln = t & 63;
    const int lc = ln & 15, g = ln >> 4;

#pragma unroll
    for (int mm = 0; mm < 4; mm++) {
        const int cg = t + mm * 256;           // chunk 0..1023
        const int lrow = cg >> 5, phys = cg & 31;
        const int logical = (phys & 24) | ((phys & 7) ^ (lrow & 7));
        gld16(xt + ((size_t)(b * L + l0 + lrow)) * 256 + logical * 8,
              xlds + (size_t)(w * 64 + mm * 256) * 8);
    }
    __syncthreads();

    f4 acc[5][2];
#pragma unroll
    for (int rt = 0; rt < 5; rt++) {
        const int row0 = (w * 5 + rt) * 16 + g * 4;
        const float4 bi = *(const float4*)(ball + row0);
#pragma unroll
        for (int ct = 0; ct < 2; ct++) {
            acc[rt][ct].x = bi.x; acc[rt][ct].y = bi.y;
            acc[rt][ct].z = bi.z; acc[rt][ct].w = bi.w;
        }
    }

#pragma unroll
    for (int k = 0; k < 8; k++) {
        bf8 bfr[2];
#pragma unroll
        for (int ct = 0; ct < 2; ct++) {
            const int lrow = ct * 16 + lc;
            const int lchunk = k * 4 + g;
            const int phys = (lchunk & 24) | ((lchunk & 7) ^ (lrow & 7));
            bfr[ct] = *(const bf8*)(xlds + (size_t)lrow * 256 + phys * 8);
        }
#pragma unroll
        for (int rt = 0; rt < 5; rt++) {
            const bf8 af = *(const bf8*)(Wall +
                (size_t)((w * 5 + rt) * 16 + lc) * 256 + k * 32 + g * 8);
#pragma unroll
            for (int ct = 0; ct < 2; ct++)
                acc[rt][ct] = __builtin_amdgcn_mfma_f32_16x16x32_bf16(
                    af, bfr[ct], acc[rt][ct], 0, 0, 0);
        }
    }

    const float Q_SCALE = 1.44269504f;   // log2(e)
#pragma unroll
    for (int rt = 0; rt < 5; rt++) {
        const int rg = w * 5 + rt;
        const int row0 = rg * 16 + g * 4;
#pragma unroll
        for (int ct = 0; ct < 2; ct++) {
            const int l = l0 + ct * 16 + lc;
            const f4 a = acc[rt][ct];
            if (rg < 2) {
                uint2 o;
                o.x = f2bf(a.x * Q_SCALE) | ((unsigned)f2bf(a.y * Q_SCALE) << 16);
                o.y = f2bf(a.z * Q_SCALE) | ((unsigned)f2bf(a.w * Q_SCALE) << 16);
                *(uint2*)(qt + ((size_t)(b * L + l)) * 32 + row0) = o;
            } else if (rg < 4) {
                uint2 o;
                o.x = f2bf(a.x) | ((unsigned)f2bf(a.y) << 16);
                o.y = f2bf(a.z) | ((unsigned)f2bf(a.w) << 16);
                *(uint2*)(kt + ((size_t)(b * L + l)) * 32 + (row0 - 32)) = o;
            } else {
                const int c = row0 - 64;
                vv[((size_t)(b * C + c + 0)) * L + l] = f2bf(a.x);
                vv[((size_t)(b * C + c + 1)) * L + l] = f2bf(a.y);
                vv[((size_t)(b * C + c + 2)) * L + l] = f2bf(a.z);
                vv[((size_t)(b * C + c + 3)) * L + l] = f2bf(a.w);
            }
        }
    }
}

// ---------------------------------------------------------------------------
// attn: R13-structure split-j flash partial (measured best). Block (win,bx):
// 64 i-rows, j in [s*512,+512). Wave w: softmax owner of i-tile w (1 QK
// MFMA-pair), PV owner of c-quarter w*64. V staged block-cooperatively via
// gld16 dbuf, both-sides chunk-XOR swizzle. K in regs prefetched 1 tile.
// ps[64][40] (80B rows). 2 barriers/tile. ex2 softmax (Q pre-scaled).
// DELTA vs R13: psum shfl_xor pair moved AFTER PV (off the barrier-gated
// path; R6 discipline). XCD swizzle: win=fid&31.
// ---------------------------------------------------------------------------
__global__ __launch_bounds__(256, 4) void attn(
    const u16* __restrict__ qt, const u16* __restrict__ kt,
    const u16* __restrict__ vv, u16* __restrict__ po,
    float* __restrict__ plsum)
{
    __shared__ u16 vs[2][8192];    // [c 0..255][chunk 0..3], swizzled
    __shared__ u16 ps[64][40];     // P, 80B padded rows
    __shared__ float fl[64];

    const int fid = blockIdx.x;
    const int win = fid & 31, bx = fid >> 5;
    const int b = win >> 2, sidx = win & 3;
    const int t = threadIdx.x, w = t >> 6, ln = t & 63;
    const int lc = ln & 15, g = ln >> 4;
    const int i0 = bx * 64;
    const int js = sidx * JSEG;
    const int wc0 = w * 64;
    const int tb = (b * 32 + bx) * SSEG + sidx;

    const bf8 qf = *(const bf8*)(qt + ((size_t)(b * L + i0 + w * 16 + lc)) * 32 + g * 8);
    const u16* kb = kt + ((size_t)(b * L + js + lc)) * 32 + g * 8;

    // stage source: thread t owns LDS slot (c = t>>2 (+64m), s = t&3), which
    // holds global j-chunk s^(c&3). 4 lanes/row -> one 64B segment (permuted).
    const int sc = t >> 2, ss = t & 3;
    const u16* vsrc = vv + ((size_t)(b * C + sc)) * L + js + ((ss ^ (sc & 3)) * 8);

    f4 acc[4][4];
    const f4 fz = {0.f, 0.f, 0.f, 0.f};
#pragma unroll
    for (int it = 0; it < 4; it++)
#pragma unroll
        for (int ct = 0; ct < 4; ct++) acc[it][ct] = fz;
    float lsum = 0.f;

    auto stage = [&](int buf, int jt) {
        const u16* s = vsrc + jt * 32;
        u16* d = &vs[buf][0] + (size_t)(w * 64) * 8;   // + lane*16B by HW
#pragma unroll
        for (int m = 0; m < 4; m++)
            gld16(s + (size_t)(m * 64) * L, d + (size_t)(m * 256) * 8);
    };

    stage(0, 0);
    bf8 kf0 = *(const bf8*)(kb);
    bf8 kf1 = *(const bf8*)(kb + 16 * 32);
    int cur = 0;

#pragma unroll 1
    for (int jt = 0; jt < NT; jt++) {
        wait_vm0();                 // V(jt) + K-prefetch landed (tile-old)
        bar();                      // B1: tile published; all waves past PV(jt-1)
        if (jt + 1 < NT) stage(cur ^ 1, jt + 1);
        bf8 kn0 = kf0, kn1 = kf1;
        if (jt + 1 < NT) {
            kn0 = *(const bf8*)(kb + (size_t)((jt + 1) * 32) * 32);
            kn1 = *(const bf8*)(kb + (size_t)((jt + 1) * 32 + 16) * 32);
        }

        // ---- QK: S^T[j][i-tile w] ----
        const f4 s0 = __builtin_amdgcn_mfma_f32_16x16x32_bf16(kf0, qf, fz, 0, 0, 0);
        const f4 s1 = __builtin_amdgcn_mfma_f32_16x16x32_bf16(kf1, qf, fz, 0, 0, 0);

        // ---- shifted softmax numerators (2^x; Q pre-scaled) ----
        const float p0 = ex2(s0.x - SM_SHIFT2);
        const float p1 = ex2(s0.y - SM_SHIFT2);
        const float p2 = ex2(s0.z - SM_SHIFT2);
        const float p3 = ex2(s0.w - SM_SHIFT2);
        const float p4 = ex2(s1.x - SM_SHIFT2);
        const float p5 = ex2(s1.y - SM_SHIFT2);
        const float p6 = ex2(s1.z - SM_SHIFT2);
        const float p7 = ex2(s1.w - SM_SHIFT2);
        {
            uint2 o;
            o.x = f2bf(p0) | ((unsigned)f2bf(p1) << 16);
            o.y = f2bf(p2) | ((unsigned)f2bf(p3) << 16);
            *(uint2*)(&ps[w * 16 + lc][g * 4]) = o;
            o.x = f2bf(p4) | ((unsigned)f2bf(p5) << 16);
            o.y = f2bf(p6) | ((unsigned)f2bf(p7) << 16);
            *(uint2*)(&ps[w * 16 + lc][16 + g * 4]) = o;
        }
        float psum = ((p0 + p1) + (p2 + p3)) + ((p4 + p5) + (p6 + p7));

        wait_lgkm0();               // ps writes visible
        bar();                      // B2: P published

        // ---- PV: wave's c-quarter, swizzled 2-way b128 reads ----
        __builtin_amdgcn_s_setprio(1);
#pragma unroll
        for (int ct = 0; ct < 4; ct++) {
            const int c = wc0 + ct * 16 + lc;
            const bf8 vfr = *(const bf8*)(&vs[cur][0] + (size_t)c * 32 + ((g ^ (c & 3)) * 8));
#pragma unroll
            for (int it = 0; it < 4; it++) {
                const bf8 paf = *(const bf8*)(&ps[it * 16 + lc][0] + g * 8);
                acc[it][ct] = __builtin_amdgcn_mfma_f32_16x16x32_bf16(
                    paf, vfr, acc[it][ct], 0, 0, 0);
            }
        }
        __builtin_amdgcn_s_setprio(0);

        // psum cross-lane reduce AFTER PV (off the barrier-gated path)
        psum += __shfl_xor(psum, 16);
        psum += __shfl_xor(psum, 32);
        lsum += psum;

        kf0 = kn0; kf1 = kn1;
        cur ^= 1;
    }

    // ---- epilogue: normalized bf16 partial + lsum ----
    fl[w * 16 + lc] = 1.0f / lsum;              // all g write same value
    if (g == 0) plsum[(size_t)tb * 64 + w * 16 + lc] = lsum;
    wait_lgkm0();
    bar();
    u16* pob = po + ((size_t)tb * 2048 + t) * 8;
#pragma unroll
    for (int it = 0; it < 4; it++) {
        const float4 iv = *(const float4*)&fl[it * 16 + g * 4];
#pragma unroll
        for (int cp = 0; cp < 2; cp++) {
            const f4 a0 = acc[it][2 * cp];
            const f4 a1 = acc[it][2 * cp + 1];
            uint4 o;
            o.x = f2bf(a0.x * iv.x) | ((unsigned)f2bf(a0.y * iv.y) << 16);
            o.y = f2bf(a0.z * iv.z) | ((unsigned)f2bf(a0.w * iv.w) << 16);
            o.z = f2bf(a1.x * iv.x) | ((unsigned)f2bf(a1.y * iv.y) << 16);
            o.w = f2bf(a1.z * iv.z) | ((unsigned)f2bf(a1.w * iv.w) << 16);
            *(uint4*)(pob + (size_t)(it * 2 + cp) * 2048) = o;
        }
    }
}

// ---------------------------------------------------------------------------
// combine: block (bx, b, z): rows i = bx*64 + z*16 .. +15, all 256 c.
// out = gamma * sum_s (lsum_s/Σlsum) * po_s + x   (shift cancels exactly)
// ---------------------------------------------------------------------------
__global__ __launch_bounds__(256) void combine(
    const u16* __restrict__ po, const float* __restrict__ plsum,
    const float* __restrict__ x, const float* __restrict__ gamma_p,
    float* __restrict__ out)
{
    __shared__ float raw[4][16];
    __shared__ float wts[4][16];
    const int bx = blockIdx.x, b = blockIdx.y, z = blockIdx.z;
    const int t = threadIdx.x, wq = t >> 6, ln = t & 63;
    const int lc = ln & 15, g = ln >> 4;
    const int tbase = (b * 32 + bx) * SSEG;

    if (t < 64)
        raw[t >> 4][t & 15] = plsum[(size_t)(tbase + (t >> 4)) * 64 + z * 16 + (t & 15)];
    __syncthreads();
    if (t < 16) {
        const float l0 = raw[0][t], l1 = raw[1][t], l2 = raw[2][t], l3 = raw[3][t];
        const float inv = 1.0f / (((l0 + l1) + (l2 + l3)));
        wts[0][t] = l0 * inv; wts[1][t] = l1 * inv;
        wts[2][t] = l2 * inv; wts[3][t] = l3 * inv;
    }
    __syncthreads();

    f4 tot[4];
    const f4 fz = {0.f, 0.f, 0.f, 0.f};
#pragma unroll
    for (int ct = 0; ct < 4; ct++) tot[ct] = fz;

#pragma unroll
    for (int s = 0; s < SSEG; s++) {
        const u16* base = po + ((size_t)(tbase + s) * 2048 + (size_t)z * 2 * 256 + t) * 8;
        const uint4 q0 = *(const uint4*)base;
        const uint4 q1 = *(const uint4*)(base + 2048);
        const float4 wv = *(const float4*)&wts[s][g * 4];
        tot[0].x += wv.x * bfl(q0.x); tot[0].y += wv.y * bfh(q0.x);
        tot[0].z += wv.z * bfl(q0.y); tot[0].w += wv.w * bfh(q0.y);
        tot[1].x += wv.x * bfl(q0.z); tot[1].y += wv.y * bfh(q0.z);
        tot[1].z += wv.z * bfl(q0.w); tot[1].w += wv.w * bfh(q0.w);
        tot[2].x += wv.x * bfl(q1.x); tot[2].y += wv.y * bfh(q1.x);
        tot[2].z += wv.z * bfl(q1.y); tot[2].w += wv.w * bfh(q1.y);
        tot[3].x += wv.x * bfl(q1.z); tot[3].y += wv.y * bfh(q1.z);
        tot[3].z += wv.z * bfl(q1.w); tot[3].w += wv.w * bfh(q1.w);
    }

    const float gmm = gamma_p[0];
#pragma unroll
    for (int ct = 0; ct < 4; ct++) {
        const int c = wq * 64 + ct * 16 + lc;
        const size_t adr = ((size_t)(b * C + c)) * L + bx * 64 + z * 16 + g * 4;
        const float4 xv = *(const float4*)(x + adr);
        float4 o;
        o.x = gmm * tot[ct].x + xv.x;
        o.y = gmm * tot[ct].y + xv.y;
        o.z = gmm * tot[ct].z + xv.z;
        o.w = gmm * tot[ct].w + xv.w;
        *(float4*)(out + adr) = o;
    }
}

extern "C" void kernel_launch(void* const* d_in, const int* in_sizes, int n_in,
                              void* d_out, int out_size, void* d_ws, size_t ws_size,
                              hipStream_t stream) {
    const float* x  = (const float*)d_in[0];
    const float* Wq = (const float*)d_in[1];
    const float* bq = (const float*)d_in[2];
    const float* Wk = (const float*)d_in[3];
    const float* bk = (const float*)d_in[4];
    const float* Wv = (const float*)d_in[5];
    const float* bv = (const float*)d_in[6];
    const float* gm = (const float*)d_in[7];
    float* out = (float*)d_out;

    // ws layout (u16 units). po overlays xt (xt dead once proj completes).
    u16* vvp  = (u16*)d_ws;                          // B*C*L      (8 MB)
    u16* qtp  = vvp + (size_t)B * C * L;             // B*L*CQK    (1 MB)
    u16* ktp  = qtp + (size_t)B * L * CQK;           // B*L*CQK    (1 MB)
    u16* Wall = ktp + (size_t)B * L * CQK;           // 320*256    (160 KB)
    float* ball = (float*)(Wall + 320 * 256);        // 320 fp32
    u16* xt   = Wall + 320 * 256 + 640;              // B*L*C      (8 MB)
    u16* po   = xt;                                  // 32 MB partials
    float* plsum = (float*)(po + (size_t)B * 32 * SSEG * 2048 * 8);  // 64K fp32

    prep<<<1104, 256, 0, stream>>>(x, xt, Wq, bq, Wk, bk, Wv, bv, Wall, ball);
    proj<<<dim3(L / 32, B), 256, 0, stream>>>(xt, Wall, ball, qtp, ktp, vvp);
    attn<<<1024, 256, 0, stream>>>(qtp, ktp, vvp, po, plsum);
    combine<<<dim3(L / 64, B, SSEG), 256, 0, stream>>>(po, plsum, x, gm, out);
}

// Round 19
// 66.161 us; speedup vs baseline: 1.3322x; 1.0249x over previous
//
#include <hip/hip_runtime.h>

#define B 8
#define C 256
#define L 2048
#define CQK 32
#define SSEG 4
#define JSEG (L / SSEG)      // 512
#define NT (JSEG / 32)       // 16 j-tiles per block
#define SM_SHIFT2 28.8539008f   // 20 * log2(e); Q pre-scaled by log2(e)

typedef unsigned short u16;
typedef __attribute__((ext_vector_type(8))) short bf8;   // 8 bf16 = 4 VGPR
typedef __attribute__((ext_vector_type(4))) float f4;    // mfma C/D

__device__ __forceinline__ u16 f2bf(float f) {
    union { float f; unsigned u; } v; v.f = f;
    unsigned r = v.u + 0x7FFFu + ((v.u >> 16) & 1u);   // RNE
    return (u16)(r >> 16);
}
__device__ __forceinline__ float bfl(unsigned u) {
    union { unsigned u; float f; } v; v.u = u << 16; return v.f;
}
__device__ __forceinline__ float bfh(unsigned u) {
    union { unsigned u; float f; } v; v.u = u & 0xFFFF0000u; return v.f;
}
__device__ __forceinline__ unsigned cvtpk(float lo, float hi) {
    unsigned r;
    asm("v_cvt_pk_bf16_f32 %0, %1, %2" : "=v"(r) : "v"(lo), "v"(hi));
    return r;
}
__device__ __forceinline__ float ex2(float x) {   // 2^x
    float r;
    asm("v_exp_f32 %0, %1" : "=v"(r) : "v"(x));
    return r;
}

__device__ __forceinline__ void gld16(const u16* gp, u16* lp) {
    auto* g1 = (const __attribute__((address_space(1))) u16*)gp;
    auto* l3 = (__attribute__((address_space(3))) u16*)lp;
    __builtin_amdgcn_global_load_lds(g1, l3, 16, 0, 0);
}
__device__ __forceinline__ void wait_vm0() {
    asm volatile("s_waitcnt vmcnt(0)" ::: "memory");
    __builtin_amdgcn_sched_barrier(0);
}
__device__ __forceinline__ void wait_lgkm0() {
    asm volatile("s_waitcnt lgkmcnt(0)" ::: "memory");
    __builtin_amdgcn_sched_barrier(0);
}
__device__ __forceinline__ void bar() {
    __builtin_amdgcn_sched_barrier(0);
    __builtin_amdgcn_s_barrier();
    __builtin_amdgcn_sched_barrier(0);
}

// ---------------------------------------------------------------------------
// prep: merged xconv (blocks 0..1023) + wconv (blocks 1024..1103).
// ---------------------------------------------------------------------------
__global__ __launch_bounds__(256) void prep(
    const float* __restrict__ x, u16* __restrict__ xt,
    const float* __restrict__ Wq, const float* __restrict__ bq,
    const float* __restrict__ Wk, const float* __restrict__ bk,
    const float* __restrict__ Wv, const float* __restrict__ bv,
    u16* __restrict__ Wall, float* __restrict__ ball)
{
    __shared__ float tile[64][65];
    const int id = blockIdx.x;
    const int t = threadIdx.x;
    if (id < 1024) {
        const int l0 = (id & 31) * 64, c0 = ((id >> 5) & 3) * 64, b = id >> 7;
        const int ln = t & 63, w = t >> 6;
#pragma unroll
        for (int i = 0; i < 16; i++) {
            const int c = w * 16 + i;
            tile[c][ln] = x[((size_t)(b * C + c0 + c)) * L + l0 + ln];
        }
        __syncthreads();
        const int lrow = t >> 2, q = t & 3;
        unsigned o[8];
#pragma unroll
        for (int jj = 0; jj < 8; jj++) {
            const float a0 = tile[q * 16 + jj * 2][lrow];
            const float a1 = tile[q * 16 + jj * 2 + 1][lrow];
            o[jj] = f2bf(a0) | ((unsigned)f2bf(a1) << 16);
        }
        u16* dst = xt + ((size_t)(b * L + l0 + lrow)) * 256 + c0 + q * 16;
        *(uint4*)(dst)     = make_uint4(o[0], o[1], o[2], o[3]);
        *(uint4*)(dst + 8) = make_uint4(o[4], o[5], o[6], o[7]);
    } else {
        const int id2 = id - 1024;
        const int idx = (id2 * 256 + t) * 4;
        const int row = idx >> 8, c = idx & 255;
        const float* s;
        if (row < 32)      s = Wq + row * C + c;
        else if (row < 64) s = Wk + (row - 32) * C + c;
        else               s = Wv + (row - 64) * C + c;
        const float4 v = *(const float4*)s;
        uint2 o;
        o.x = f2bf(v.x) | ((unsigned)f2bf(v.y) << 16);
        o.y = f2bf(v.z) | ((unsigned)f2bf(v.w) << 16);
        *(uint2*)(Wall + idx) = o;
        if (id2 == 0) {
            for (int i = t; i < 320; i += 256)
                ball[i] = (i < 32) ? bq[i] : (i < 64) ? bk[i - 32] : bv[i - 64];
        }
    }
}

// ---------------------------------------------------------------------------
// proj: [320x256] x [256 x L] MFMA GEMM per batch. l-tile = 32 (grid 512).
// Q rows pre-scaled by log2(e) so attn can use raw v_exp_f32 (2^x).
// ---------------------------------------------------------------------------
__global__ __launch_bounds__(256) void proj(
    const u16* __restrict__ xt, const u16* __restrict__ Wall,
    const float* __restrict__ ball, u16* __restrict__ qt,
    u16* __restrict__ kt, u16* __restrict__ vv)
{
    __shared__ u16 xlds[32 * 256];   // 16 KB
    const int b = blockIdx.y, l0 = blockIdx.x * 32;
    const int t = threadIdx.x, w = t >> 6, ln = t & 63;
    const int lc = ln & 15, g = ln >> 4;

#pragma unroll
    for (int mm = 0; mm < 4; mm++) {
        const int cg = t + mm * 256;           // chunk 0..1023
        const int lrow = cg >> 5, phys = cg & 31;
        const int logical = (phys & 24) | ((phys & 7) ^ (lrow & 7));
        gld16(xt + ((size_t)(b * L + l0 + lrow)) * 256 + logical * 8,
              xlds + (size_t)(w * 64 + mm * 256) * 8);
    }
    __syncthreads();

    f4 acc[5][2];
#pragma unroll
    for (int rt = 0; rt < 5; rt++) {
        const int row0 = (w * 5 + rt) * 16 + g * 4;
        const float4 bi = *(const float4*)(ball + row0);
#pragma unroll
        for (int ct = 0; ct < 2; ct++) {
            acc[rt][ct].x = bi.x; acc[rt][ct].y = bi.y;
            acc[rt][ct].z = bi.z; acc[rt][ct].w = bi.w;
        }
    }

#pragma unroll
    for (int k = 0; k < 8; k++) {
        bf8 bfr[2];
#pragma unroll
        for (int ct = 0; ct < 2; ct++) {
            const int lrow = ct * 16 + lc;
            const int lchunk = k * 4 + g;
            const int phys = (lchunk & 24) | ((lchunk & 7) ^ (lrow & 7));
            bfr[ct] = *(const bf8*)(xlds + (size_t)lrow * 256 + phys * 8);
        }
#pragma unroll
        for (int rt = 0; rt < 5; rt++) {
            const bf8 af = *(const bf8*)(Wall +
                (size_t)((w * 5 + rt) * 16 + lc) * 256 + k * 32 + g * 8);
#pragma unroll
            for (int ct = 0; ct < 2; ct++)
                acc[rt][ct] = __builtin_amdgcn_mfma_f32_16x16x32_bf16(
                    af, bfr[ct], acc[rt][ct], 0, 0, 0);
        }
    }

    const float Q_SCALE = 1.44269504f;   // log2(e)
#pragma unroll
    for (int rt = 0; rt < 5; rt++) {
        const int rg = w * 5 + rt;
        const int row0 = rg * 16 + g * 4;
#pragma unroll
        for (int ct = 0; ct < 2; ct++) {
            const int l = l0 + ct * 16 + lc;
            const f4 a = acc[rt][ct];
            if (rg < 2) {
                uint2 o;
                o.x = f2bf(a.x * Q_SCALE) | ((unsigned)f2bf(a.y * Q_SCALE) << 16);
                o.y = f2bf(a.z * Q_SCALE) | ((unsigned)f2bf(a.w * Q_SCALE) << 16);
                *(uint2*)(qt + ((size_t)(b * L + l)) * 32 + row0) = o;
            } else if (rg < 4) {
                uint2 o;
                o.x = f2bf(a.x) | ((unsigned)f2bf(a.y) << 16);
                o.y = f2bf(a.z) | ((unsigned)f2bf(a.w) << 16);
                *(uint2*)(kt + ((size_t)(b * L + l)) * 32 + (row0 - 32)) = o;
            } else {
                const int c = row0 - 64;
                vv[((size_t)(b * C + c + 0)) * L + l] = f2bf(a.x);
                vv[((size_t)(b * C + c + 1)) * L + l] = f2bf(a.y);
                vv[((size_t)(b * C + c + 2)) * L + l] = f2bf(a.z);
                vv[((size_t)(b * C + c + 3)) * L + l] = f2bf(a.w);
            }
        }
    }
}

// ---------------------------------------------------------------------------
// attn: R18-structure split-j flash partial (measured best). DELTA vs R18:
// ps-row packing via v_cvt_pk_bf16_f32 (4 instr replace ~28 VALU of f2bf
// chains on the barrier-gated path); epilogue packing likewise.
// ---------------------------------------------------------------------------
__global__ __launch_bounds__(256, 4) void attn(
    const u16* __restrict__ qt, const u16* __restrict__ kt,
    const u16* __restrict__ vv, u16* __restrict__ po,
    float* __restrict__ plsum)
{
    __shared__ u16 vs[2][8192];    // [c 0..255][chunk 0..3], swizzled
    __shared__ u16 ps[64][40];     // P, 80B padded rows
    __shared__ float fl[64];

    const int fid = blockIdx.x;
    const int win = fid & 31, bx = fid >> 5;
    const int b = win >> 2, sidx = win & 3;
    const int t = threadIdx.x, w = t >> 6, ln = t & 63;
    const int lc = ln & 15, g = ln >> 4;
    const int i0 = bx * 64;
    const int js = sidx * JSEG;
    const int wc0 = w * 64;
    const int tb = (b * 32 + bx) * SSEG + sidx;

    const bf8 qf = *(const bf8*)(qt + ((size_t)(b * L + i0 + w * 16 + lc)) * 32 + g * 8);
    const u16* kb = kt + ((size_t)(b * L + js + lc)) * 32 + g * 8;

    // stage source: thread t owns LDS slot (c = t>>2 (+64m), s = t&3), which
    // holds global j-chunk s^(c&3). 4 lanes/row -> one 64B segment (permuted).
    const int sc = t >> 2, ss = t & 3;
    const u16* vsrc = vv + ((size_t)(b * C + sc)) * L + js + ((ss ^ (sc & 3)) * 8);

    f4 acc[4][4];
    const f4 fz = {0.f, 0.f, 0.f, 0.f};
#pragma unroll
    for (int it = 0; it < 4; it++)
#pragma unroll
        for (int ct = 0; ct < 4; ct++) acc[it][ct] = fz;
    float lsum = 0.f;

    auto stage = [&](int buf, int jt) {
        const u16* s = vsrc + jt * 32;
        u16* d = &vs[buf][0] + (size_t)(w * 64) * 8;   // + lane*16B by HW
#pragma unroll
        for (int m = 0; m < 4; m++)
            gld16(s + (size_t)(m * 64) * L, d + (size_t)(m * 256) * 8);
    };

    stage(0, 0);
    bf8 kf0 = *(const bf8*)(kb);
    bf8 kf1 = *(const bf8*)(kb + 16 * 32);
    int cur = 0;

#pragma unroll 1
    for (int jt = 0; jt < NT; jt++) {
        wait_vm0();                 // V(jt) + K-prefetch landed (tile-old)
        bar();                      // B1: tile published; all waves past PV(jt-1)
        if (jt + 1 < NT) stage(cur ^ 1, jt + 1);
        bf8 kn0 = kf0, kn1 = kf1;
        if (jt + 1 < NT) {
            kn0 = *(const bf8*)(kb + (size_t)((jt + 1) * 32) * 32);
            kn1 = *(const bf8*)(kb + (size_t)((jt + 1) * 32 + 16) * 32);
        }

        // ---- QK: S^T[j][i-tile w] ----
        const f4 s0 = __builtin_amdgcn_mfma_f32_16x16x32_bf16(kf0, qf, fz, 0, 0, 0);
        const f4 s1 = __builtin_amdgcn_mfma_f32_16x16x32_bf16(kf1, qf, fz, 0, 0, 0);

        // ---- shifted softmax numerators (2^x; Q pre-scaled) ----
        const float p0 = ex2(s0.x - SM_SHIFT2);
        const float p1 = ex2(s0.y - SM_SHIFT2);
        const float p2 = ex2(s0.z - SM_SHIFT2);
        const float p3 = ex2(s0.w - SM_SHIFT2);
        const float p4 = ex2(s1.x - SM_SHIFT2);
        const float p5 = ex2(s1.y - SM_SHIFT2);
        const float p6 = ex2(s1.z - SM_SHIFT2);
        const float p7 = ex2(s1.w - SM_SHIFT2);
        {
            uint2 o;
            o.x = cvtpk(p0, p1);
            o.y = cvtpk(p2, p3);
            *(uint2*)(&ps[w * 16 + lc][g * 4]) = o;
            o.x = cvtpk(p4, p5);
            o.y = cvtpk(p6, p7);
            *(uint2*)(&ps[w * 16 + lc][16 + g * 4]) = o;
        }
        float psum = ((p0 + p1) + (p2 + p3)) + ((p4 + p5) + (p6 + p7));

        wait_lgkm0();               // ps writes visible
        bar();                      // B2: P published

        // ---- PV: wave's c-quarter, swizzled 2-way b128 reads ----
        __builtin_amdgcn_s_setprio(1);
#pragma unroll
        for (int ct = 0; ct < 4; ct++) {
            const int c = wc0 + ct * 16 + lc;
            const bf8 vfr = *(const bf8*)(&vs[cur][0] + (size_t)c * 32 + ((g ^ (c & 3)) * 8));
#pragma unroll
            for (int it = 0; it < 4; it++) {
                const bf8 paf = *(const bf8*)(&ps[it * 16 + lc][0] + g * 8);
                acc[it][ct] = __builtin_amdgcn_mfma_f32_16x16x32_bf16(
                    paf, vfr, acc[it][ct], 0, 0, 0);
            }
        }
        __builtin_amdgcn_s_setprio(0);

        // psum cross-lane reduce AFTER PV (off the barrier-gated path)
        psum += __shfl_xor(psum, 16);
        psum += __shfl_xor(psum, 32);
        lsum += psum;

        kf0 = kn0; kf1 = kn1;
        cur ^= 1;
    }

    // ---- epilogue: normalized bf16 partial + lsum ----
    fl[w * 16 + lc] = 1.0f / lsum;              // all g write same value
    if (g == 0) plsum[(size_t)tb * 64 + w * 16 + lc] = lsum;
    wait_lgkm0();
    bar();
    u16* pob = po + ((size_t)tb * 2048 + t) * 8;
#pragma unroll
    for (int it = 0; it < 4; it++) {
        const float4 iv = *(const float4*)&fl[it * 16 + g * 4];
#pragma unroll
        for (int cp = 0; cp < 2; cp++) {
            const f4 a0 = acc[it][2 * cp];
            const f4 a1 = acc[it][2 * cp + 1];
            uint4 o;
            o.x = cvtpk(a0.x * iv.x, a0.y * iv.y);
            o.y = cvtpk(a0.z * iv.z, a0.w * iv.w);
            o.z = cvtpk(a1.x * iv.x, a1.y * iv.y);
            o.w = cvtpk(a1.z * iv.z, a1.w * iv.w);
            *(uint4*)(pob + (size_t)(it * 2 + cp) * 2048) = o;
        }
    }
}

// ---------------------------------------------------------------------------
// combine: block (bx, b, z): rows i = bx*64 + z*16 .. +15, all 256 c.
// out = gamma * sum_s (lsum_s/Σlsum) * po_s + x   (shift cancels exactly)
// ---------------------------------------------------------------------------
__global__ __launch_bounds__(256) void combine(
    const u16* __restrict__ po, const float* __restrict__ plsum,
    const float* __restrict__ x, const float* __restrict__ gamma_p,
    float* __restrict__ out)
{
    __shared__ float raw[4][16];
    __shared__ float wts[4][16];
    const int bx = blockIdx.x, b = blockIdx.y, z = blockIdx.z;
    const int t = threadIdx.x, wq = t >> 6, ln = t & 63;
    const int lc = ln & 15, g = ln >> 4;
    const int tbase = (b * 32 + bx) * SSEG;

    if (t < 64)
        raw[t >> 4][t & 15] = plsum[(size_t)(tbase + (t >> 4)) * 64 + z * 16 + (t & 15)];
    __syncthreads();
    if (t < 16) {
        const float l0 = raw[0][t], l1 = raw[1][t], l2 = raw[2][t], l3 = raw[3][t];
        const float inv = 1.0f / (((l0 + l1) + (l2 + l3)));
        wts[0][t] = l0 * inv; wts[1][t] = l1 * inv;
        wts[2][t] = l2 * inv; wts[3][t] = l3 * inv;
    }
    __syncthreads();

    f4 tot[4];
    const f4 fz = {0.f, 0.f, 0.f, 0.f};
#pragma unroll
    for (int ct = 0; ct < 4; ct++) tot[ct] = fz;

#pragma unroll
    for (int s = 0; s < SSEG; s++) {
        const u16* base = po + ((size_t)(tbase + s) * 2048 + (size_t)z * 2 * 256 + t) * 8;
        const uint4 q0 = *(const uint4*)base;
        const uint4 q1 = *(const uint4*)(base + 2048);
        const float4 wv = *(const float4*)&wts[s][g * 4];
        tot[0].x += wv.x * bfl(q0.x); tot[0].y += wv.y * bfh(q0.x);
        tot[0].z += wv.z * bfl(q0.y); tot[0].w += wv.w * bfh(q0.y);
        tot[1].x += wv.x * bfl(q0.z); tot[1].y += wv.y * bfh(q0.z);
        tot[1].z += wv.z * bfl(q0.w); tot[1].w += wv.w * bfh(q0.w);
        tot[2].x += wv.x * bfl(q1.x); tot[2].y += wv.y * bfh(q1.x);
        tot[2].z += wv.z * bfl(q1.y); tot[2].w += wv.w * bfh(q1.y);
        tot[3].x += wv.x * bfl(q1.z); tot[3].y += wv.y * bfh(q1.z);
        tot[3].z += wv.z * bfl(q1.w); tot[3].w += wv.w * bfh(q1.w);
    }

    const float gmm = gamma_p[0];
#pragma unroll
    for (int ct = 0; ct < 4; ct++) {
        const int c = wq * 64 + ct * 16 + lc;
        const size_t adr = ((size_t)(b * C + c)) * L + bx * 64 + z * 16 + g * 4;
        const float4 xv = *(const float4*)(x + adr);
        float4 o;
        o.x = gmm * tot[ct].x + xv.x;
        o.y = gmm * tot[ct].y + xv.y;
        o.z = gmm * tot[ct].z + xv.z;
        o.w = gmm * tot[ct].w + xv.w;
        *(float4*)(out + adr) = o;
    }
}

extern "C" void kernel_launch(void* const* d_in, const int* in_sizes, int n_in,
                              void* d_out, int out_size, void* d_ws, size_t ws_size,
                              hipStream_t stream) {
    const float* x  = (const float*)d_in[0];
    const float* Wq = (const float*)d_in[1];
    const float* bq = (const float*)d_in[2];
    const float* Wk = (const float*)d_in[3];
    const float* bk = (const float*)d_in[4];
    const float* Wv = (const float*)d_in[5];
    const float* bv = (const float*)d_in[6];
    const float* gm = (const float*)d_in[7];
    float* out = (float*)d_out;

    // ws layout (u16 units). po overlays xt (xt dead once proj completes).
    u16* vvp  = (u16*)d_ws;                          // B*C*L      (8 MB)
    u16* qtp  = vvp + (size_t)B * C * L;             // B*L*CQK    (1 MB)
    u16* ktp  = qtp + (size_t)B * L * CQK;           // B*L*CQK    (1 MB)
    u16* Wall = ktp + (size_t)B * L * CQK;           // 320*256    (160 KB)
    float* ball = (float*)(Wall + 320 * 256);        // 320 fp32
    u16* xt   = Wall + 320 * 256 + 640;              // B*L*C      (8 MB)
    u16* po   = xt;                                  // 32 MB partials
    float* plsum = (float*)(po + (size_t)B * 32 * SSEG * 2048 * 8);  // 64K fp32

    prep<<<1104, 256, 0, stream>>>(x, xt, Wq, bq, Wk, bk, Wv, bv, Wall, ball);
    proj<<<dim3(L / 32, B), 256, 0, stream>>>(xt, Wall, ball, qtp, ktp, vvp);
    attn<<<1024, 256, 0, stream>>>(qtp, ktp, vvp, po, plsum);
    combine<<<dim3(L / 64, B, SSEG), 256, 0, stream>>>(po, plsum, x, gm, out);
}

// Round 20
// 65.600 us; speedup vs baseline: 1.3436x; 1.0085x over previous
//
#include <hip/hip_runtime.h>

#define B 8
#define C 256
#define L 2048
#define CQK 32
#define SSEG 4
#define JSEG (L / SSEG)      // 512
#define NT (JSEG / 32)       // 16 j-tiles per block
#define SM_SHIFT2 28.8539008f   // 20 * log2(e); Q pre-scaled by log2(e)

typedef unsigned short u16;
typedef __attribute__((ext_vector_type(8))) short bf8;   // 8 bf16 = 4 VGPR
typedef __attribute__((ext_vector_type(4))) float f4;    // mfma C/D

__device__ __forceinline__ u16 f2bf(float f) {
    union { float f; unsigned u; } v; v.f = f;
    unsigned r = v.u + 0x7FFFu + ((v.u >> 16) & 1u);   // RNE
    return (u16)(r >> 16);
}
__device__ __forceinline__ float bfl(unsigned u) {
    union { unsigned u; float f; } v; v.u = u << 16; return v.f;
}
__device__ __forceinline__ float bfh(unsigned u) {
    union { unsigned u; float f; } v; v.u = u & 0xFFFF0000u; return v.f;
}
__device__ __forceinline__ unsigned cvtpk(float lo, float hi) {
    unsigned r;
    asm("v_cvt_pk_bf16_f32 %0, %1, %2" : "=v"(r) : "v"(lo), "v"(hi));
    return r;
}
__device__ __forceinline__ float ex2(float x) {   // 2^x
    float r;
    asm("v_exp_f32 %0, %1" : "=v"(r) : "v"(x));
    return r;
}

__device__ __forceinline__ void gld16(const u16* gp, u16* lp) {
    auto* g1 = (const __attribute__((address_space(1))) u16*)gp;
    auto* l3 = (__attribute__((address_space(3))) u16*)lp;
    __builtin_amdgcn_global_load_lds(g1, l3, 16, 0, 0);
}
__device__ __forceinline__ void wait_vm0() {
    asm volatile("s_waitcnt vmcnt(0)" ::: "memory");
    __builtin_amdgcn_sched_barrier(0);
}
__device__ __forceinline__ void wait_lgkm0() {
    asm volatile("s_waitcnt lgkmcnt(0)" ::: "memory");
    __builtin_amdgcn_sched_barrier(0);
}
__device__ __forceinline__ void bar() {
    __builtin_amdgcn_sched_barrier(0);
    __builtin_amdgcn_s_barrier();
    __builtin_amdgcn_sched_barrier(0);
}

// ---------------------------------------------------------------------------
// prep: merged xconv (blocks 0..1023) + wconv (blocks 1024..1103).
// ---------------------------------------------------------------------------
__global__ __launch_bounds__(256) void prep(
    const float* __restrict__ x, u16* __restrict__ xt,
    const float* __restrict__ Wq, const float* __restrict__ bq,
    const float* __restrict__ Wk, const float* __restrict__ bk,
    const float* __restrict__ Wv, const float* __restrict__ bv,
    u16* __restrict__ Wall, float* __restrict__ ball)
{
    __shared__ float tile[64][65];
    const int id = blockIdx.x;
    const int t = threadIdx.x;
    if (id < 1024) {
        const int l0 = (id & 31) * 64, c0 = ((id >> 5) & 3) * 64, b = id >> 7;
        const int ln = t & 63, w = t >> 6;
#pragma unroll
        for (int i = 0; i < 16; i++) {
            const int c = w * 16 + i;
            tile[c][ln] = x[((size_t)(b * C + c0 + c)) * L + l0 + ln];
        }
        __syncthreads();
        const int lrow = t >> 2, q = t & 3;
        unsigned o[8];
#pragma unroll
        for (int jj = 0; jj < 8; jj++) {
            const float a0 = tile[q * 16 + jj * 2][lrow];
            const float a1 = tile[q * 16 + jj * 2 + 1][lrow];
            o[jj] = f2bf(a0) | ((unsigned)f2bf(a1) << 16);
        }
        u16* dst = xt + ((size_t)(b * L + l0 + lrow)) * 256 + c0 + q * 16;
        *(uint4*)(dst)     = make_uint4(o[0], o[1], o[2], o[3]);
        *(uint4*)(dst + 8) = make_uint4(o[4], o[5], o[6], o[7]);
    } else {
        const int id2 = id - 1024;
        const int idx = (id2 * 256 + t) * 4;
        const int row = idx >> 8, c = idx & 255;
        const float* s;
        if (row < 32)      s = Wq + row * C + c;
        else if (row < 64) s = Wk + (row - 32) * C + c;
        else               s = Wv + (row - 64) * C + c;
        const float4 v = *(const float4*)s;
        uint2 o;
        o.x = f2bf(v.x) | ((unsigned)f2bf(v.y) << 16);
        o.y = f2bf(v.z) | ((unsigned)f2bf(v.w) << 16);
        *(uint2*)(Wall + idx) = o;
        if (id2 == 0) {
            for (int i = t; i < 320; i += 256)
                ball[i] = (i < 32) ? bq[i] : (i < 64) ? bk[i - 32] : bv[i - 64];
        }
    }
}

// ---------------------------------------------------------------------------
// proj: [320x256] x [256 x L] MFMA GEMM per batch. l-tile = 32 (grid 512).
// Q rows pre-scaled by log2(e) so attn can use raw v_exp_f32 (2^x).
// ---------------------------------------------------------------------------
__global__ __launch_bounds__(256) void proj(
    const u16* __restrict__ xt, const u16* __restrict__ Wall,
    const float* __restrict__ ball, u16* __restrict__ qt,
    u16* __restrict__ kt, u16* __restrict__ vv)
{
    __shared__ u16 xlds[32 * 256];   // 16 KB
    const int b = blockIdx.y, l0 = blockIdx.x * 32;
    const int t = threadIdx.x, w = t >> 6, ln = t & 63;
    const int lc = ln & 15, g = ln >> 4;

#pragma unroll
    for (int mm = 0; mm < 4; mm++) {
        const int cg = t + mm * 256;           // chunk 0..1023
        const int lrow = cg >> 5, phys = cg & 31;
        const int logical = (phys & 24) | ((phys & 7) ^ (lrow & 7));
        gld16(xt + ((size_t)(b * L + l0 + lrow)) * 256 + logical * 8,
              xlds + (size_t)(w * 64 + mm * 256) * 8);
    }
    __syncthreads();

    f4 acc[5][2];
#pragma unroll
    for (int rt = 0; rt < 5; rt++) {
        const int row0 = (w * 5 + rt) * 16 + g * 4;
        const float4 bi = *(const float4*)(ball + row0);
#pragma unroll
        for (int ct = 0; ct < 2; ct++) {
            acc[rt][ct].x = bi.x; acc[rt][ct].y = bi.y;
            acc[rt][ct].z = bi.z; acc[rt][ct].w = bi.w;
        }
    }

#pragma unroll
    for (int k = 0; k < 8; k++) {
        bf8 bfr[2];
#pragma unroll
        for (int ct = 0; ct < 2; ct++) {
            const int lrow = ct * 16 + lc;
            const int lchunk = k * 4 + g;
            const int phys = (lchunk & 24) | ((lchunk & 7) ^ (lrow & 7));
            bfr[ct] = *(const bf8*)(xlds + (size_t)lrow * 256 + phys * 8);
        }
#pragma unroll
        for (int rt = 0; rt < 5; rt++) {
            const bf8 af = *(const bf8*)(Wall +
                (size_t)((w * 5 + rt) * 16 + lc) * 256 + k * 32 + g * 8);
#pragma unroll
            for (int ct = 0; ct < 2; ct++)
                acc[rt][ct] = __builtin_amdgcn_mfma_f32_16x16x32_bf16(
                    af, bfr[ct], acc[rt][ct], 0, 0, 0);
        }
    }

    const float Q_SCALE = 1.44269504f;   // log2(e)
#pragma unroll
    for (int rt = 0; rt < 5; rt++) {
        const int rg = w * 5 + rt;
        const int row0 = rg * 16 + g * 4;
#pragma unroll
        for (int ct = 0; ct < 2; ct++) {
            const int l = l0 + ct * 16 + lc;
            const f4 a = acc[rt][ct];
            if (rg < 2) {
                uint2 o;
                o.x = f2bf(a.x * Q_SCALE) | ((unsigned)f2bf(a.y * Q_SCALE) << 16);
                o.y = f2bf(a.z * Q_SCALE) | ((unsigned)f2bf(a.w * Q_SCALE) << 16);
                *(uint2*)(qt + ((size_t)(b * L + l)) * 32 + row0) = o;
            } else if (rg < 4) {
                uint2 o;
                o.x = f2bf(a.x) | ((unsigned)f2bf(a.y) << 16);
                o.y = f2bf(a.z) | ((unsigned)f2bf(a.w) << 16);
                *(uint2*)(kt + ((size_t)(b * L + l)) * 32 + (row0 - 32)) = o;
            } else {
                const int c = row0 - 64;
                vv[((size_t)(b * C + c + 0)) * L + l] = f2bf(a.x);
                vv[((size_t)(b * C + c + 1)) * L + l] = f2bf(a.y);
                vv[((size_t)(b * C + c + 2)) * L + l] = f2bf(a.z);
                vv[((size_t)(b * C + c + 3)) * L + l] = f2bf(a.w);
            }
        }
    }
}

// ---------------------------------------------------------------------------
// attn: R19-structure split-j flash partial (measured best). DELTA vs R19:
// (1) paf[4] fragments hoisted out of the ct-loop (PV LDS reads 20 -> 8
// per lane per tile); (2) setprio(1) extended over QK+exp (head of the
// barrier-gated chain), not just PV.
// ---------------------------------------------------------------------------
__global__ __launch_bounds__(256, 4) void attn(
    const u16* __restrict__ qt, const u16* __restrict__ kt,
    const u16* __restrict__ vv, u16* __restrict__ po,
    float* __restrict__ plsum)
{
    __shared__ u16 vs[2][8192];    // [c 0..255][chunk 0..3], swizzled
    __shared__ u16 ps[64][40];     // P, 80B padded rows
    __shared__ float fl[64];

    const int fid = blockIdx.x;
    const int win = fid & 31, bx = fid >> 5;
    const int b = win >> 2, sidx = win & 3;
    const int t = threadIdx.x, w = t >> 6, ln = t & 63;
    const int lc = ln & 15, g = ln >> 4;
    const int i0 = bx * 64;
    const int js = sidx * JSEG;
    const int wc0 = w * 64;
    const int tb = (b * 32 + bx) * SSEG + sidx;

    const bf8 qf = *(const bf8*)(qt + ((size_t)(b * L + i0 + w * 16 + lc)) * 32 + g * 8);
    const u16* kb = kt + ((size_t)(b * L + js + lc)) * 32 + g * 8;

    // stage source: thread t owns LDS slot (c = t>>2 (+64m), s = t&3), which
    // holds global j-chunk s^(c&3). 4 lanes/row -> one 64B segment (permuted).
    const int sc = t >> 2, ss = t & 3;
    const u16* vsrc = vv + ((size_t)(b * C + sc)) * L + js + ((ss ^ (sc & 3)) * 8);

    f4 acc[4][4];
    const f4 fz = {0.f, 0.f, 0.f, 0.f};
#pragma unroll
    for (int it = 0; it < 4; it++)
#pragma unroll
        for (int ct = 0; ct < 4; ct++) acc[it][ct] = fz;
    float lsum = 0.f;

    auto stage = [&](int buf, int jt) {
        const u16* s = vsrc + jt * 32;
        u16* d = &vs[buf][0] + (size_t)(w * 64) * 8;   // + lane*16B by HW
#pragma unroll
        for (int m = 0; m < 4; m++)
            gld16(s + (size_t)(m * 64) * L, d + (size_t)(m * 256) * 8);
    };

    stage(0, 0);
    bf8 kf0 = *(const bf8*)(kb);
    bf8 kf1 = *(const bf8*)(kb + 16 * 32);
    int cur = 0;

#pragma unroll 1
    for (int jt = 0; jt < NT; jt++) {
        wait_vm0();                 // V(jt) + K-prefetch landed (tile-old)
        bar();                      // B1: tile published; all waves past PV(jt-1)
        if (jt + 1 < NT) stage(cur ^ 1, jt + 1);
        bf8 kn0 = kf0, kn1 = kf1;
        if (jt + 1 < NT) {
            kn0 = *(const bf8*)(kb + (size_t)((jt + 1) * 32) * 32);
            kn1 = *(const bf8*)(kb + (size_t)((jt + 1) * 32 + 16) * 32);
        }

        // ---- QK + softmax numerators (head of gated chain, boosted) ----
        __builtin_amdgcn_s_setprio(1);
        const f4 s0 = __builtin_amdgcn_mfma_f32_16x16x32_bf16(kf0, qf, fz, 0, 0, 0);
        const f4 s1 = __builtin_amdgcn_mfma_f32_16x16x32_bf16(kf1, qf, fz, 0, 0, 0);
        const float p0 = ex2(s0.x - SM_SHIFT2);
        const float p1 = ex2(s0.y - SM_SHIFT2);
        const float p2 = ex2(s0.z - SM_SHIFT2);
        const float p3 = ex2(s0.w - SM_SHIFT2);
        const float p4 = ex2(s1.x - SM_SHIFT2);
        const float p5 = ex2(s1.y - SM_SHIFT2);
        const float p6 = ex2(s1.z - SM_SHIFT2);
        const float p7 = ex2(s1.w - SM_SHIFT2);
        {
            uint2 o;
            o.x = cvtpk(p0, p1);
            o.y = cvtpk(p2, p3);
            *(uint2*)(&ps[w * 16 + lc][g * 4]) = o;
            o.x = cvtpk(p4, p5);
            o.y = cvtpk(p6, p7);
            *(uint2*)(&ps[w * 16 + lc][16 + g * 4]) = o;
        }
        __builtin_amdgcn_s_setprio(0);
        float psum = ((p0 + p1) + (p2 + p3)) + ((p4 + p5) + (p6 + p7));

        wait_lgkm0();               // ps writes visible
        bar();                      // B2: P published

        // ---- PV: paf[4] hoisted (8 LDS reads/lane instead of 20) ----
        __builtin_amdgcn_s_setprio(1);
        bf8 paf[4];
#pragma unroll
        for (int it = 0; it < 4; it++)
            paf[it] = *(const bf8*)(&ps[it * 16 + lc][0] + g * 8);
#pragma unroll
        for (int ct = 0; ct < 4; ct++) {
            const int c = wc0 + ct * 16 + lc;
            const bf8 vfr = *(const bf8*)(&vs[cur][0] + (size_t)c * 32 + ((g ^ (c & 3)) * 8));
#pragma unroll
            for (int it = 0; it < 4; it++)
                acc[it][ct] = __builtin_amdgcn_mfma_f32_16x16x32_bf16(
                    paf[it], vfr, acc[it][ct], 0, 0, 0);
        }
        __builtin_amdgcn_s_setprio(0);

        // psum cross-lane reduce AFTER PV (off the barrier-gated path)
        psum += __shfl_xor(psum, 16);
        psum += __shfl_xor(psum, 32);
        lsum += psum;

        kf0 = kn0; kf1 = kn1;
        cur ^= 1;
    }

    // ---- epilogue: normalized bf16 partial + lsum ----
    fl[w * 16 + lc] = 1.0f / lsum;              // all g write same value
    if (g == 0) plsum[(size_t)tb * 64 + w * 16 + lc] = lsum;
    wait_lgkm0();
    bar();
    u16* pob = po + ((size_t)tb * 2048 + t) * 8;
#pragma unroll
    for (int it = 0; it < 4; it++) {
        const float4 iv = *(const float4*)&fl[it * 16 + g * 4];
#pragma unroll
        for (int cp = 0; cp < 2; cp++) {
            const f4 a0 = acc[it][2 * cp];
            const f4 a1 = acc[it][2 * cp + 1];
            uint4 o;
            o.x = cvtpk(a0.x * iv.x, a0.y * iv.y);
            o.y = cvtpk(a0.z * iv.z, a0.w * iv.w);
            o.z = cvtpk(a1.x * iv.x, a1.y * iv.y);
            o.w = cvtpk(a1.z * iv.z, a1.w * iv.w);
            *(uint4*)(pob + (size_t)(it * 2 + cp) * 2048) = o;
        }
    }
}

// ---------------------------------------------------------------------------
// combine: block (bx, b, z): rows i = bx*64 + z*16 .. +15, all 256 c.
// out = gamma * sum_s (lsum_s/Σlsum) * po_s + x   (shift cancels exactly)
// ---------------------------------------------------------------------------
__global__ __launch_bounds__(256) void combine(
    const u16* __restrict__ po, const float* __restrict__ plsum,
    const float* __restrict__ x, const float* __restrict__ gamma_p,
    float* __restrict__ out)
{
    __shared__ float raw[4][16];
    __shared__ float wts[4][16];
    const int bx = blockIdx.x, b = blockIdx.y, z = blockIdx.z;
    const int t = threadIdx.x, wq = t >> 6, ln = t & 63;
    const int lc = ln & 15, g = ln >> 4;
    const int tbase = (b * 32 + bx) * SSEG;

    if (t < 64)
        raw[t >> 4][t & 15] = plsum[(size_t)(tbase + (t >> 4)) * 64 + z * 16 + (t & 15)];
    __syncthreads();
    if (t < 16) {
        const float l0 = raw[0][t], l1 = raw[1][t], l2 = raw[2][t], l3 = raw[3][t];
        const float inv = 1.0f / (((l0 + l1) + (l2 + l3)));
        wts[0][t] = l0 * inv; wts[1][t] = l1 * inv;
        wts[2][t] = l2 * inv; wts[3][t] = l3 * inv;
    }
    __syncthreads();

    f4 tot[4];
    const f4 fz = {0.f, 0.f, 0.f, 0.f};
#pragma unroll
    for (int ct = 0; ct < 4; ct++) tot[ct] = fz;

#pragma unroll
    for (int s = 0; s < SSEG; s++) {
        const u16* base = po + ((size_t)(tbase + s) * 2048 + (size_t)z * 2 * 256 + t) * 8;
        const uint4 q0 = *(const uint4*)base;
        const uint4 q1 = *(const uint4*)(base + 2048);
        const float4 wv = *(const float4*)&wts[s][g * 4];
        tot[0].x += wv.x * bfl(q0.x); tot[0].y += wv.y * bfh(q0.x);
        tot[0].z += wv.z * bfl(q0.y); tot[0].w += wv.w * bfh(q0.y);
        tot[1].x += wv.x * bfl(q0.z); tot[1].y += wv.y * bfh(q0.z);
        tot[1].z += wv.z * bfl(q0.w); tot[1].w += wv.w * bfh(q0.w);
        tot[2].x += wv.x * bfl(q1.x); tot[2].y += wv.y * bfh(q1.x);
        tot[2].z += wv.z * bfl(q1.y); tot[2].w += wv.w * bfh(q1.y);
        tot[3].x += wv.x * bfl(q1.z); tot[3].y += wv.y * bfh(q1.z);
        tot[3].z += wv.z * bfl(q1.w); tot[3].w += wv.w * bfh(q1.w);
    }

    const float gmm = gamma_p[0];
#pragma unroll
    for (int ct = 0; ct < 4; ct++) {
        const int c = wq * 64 + ct * 16 + lc;
        const size_t adr = ((size_t)(b * C + c)) * L + bx * 64 + z * 16 + g * 4;
        const float4 xv = *(const float4*)(x + adr);
        float4 o;
        o.x = gmm * tot[ct].x + xv.x;
        o.y = gmm * tot[ct].y + xv.y;
        o.z = gmm * tot[ct].z + xv.z;
        o.w = gmm * tot[ct].w + xv.w;
        *(float4*)(out + adr) = o;
    }
}

extern "C" void kernel_launch(void* const* d_in, const int* in_sizes, int n_in,
                              void* d_out, int out_size, void* d_ws, size_t ws_size,
                              hipStream_t stream) {
    const float* x  = (const float*)d_in[0];
    const float* Wq = (const float*)d_in[1];
    const float* bq = (const float*)d_in[2];
    const float* Wk = (const float*)d_in[3];
    const float* bk = (const float*)d_in[4];
    const float* Wv = (const float*)d_in[5];
    const float* bv = (const float*)d_in[6];
    const float* gm = (const float*)d_in[7];
    float* out = (float*)d_out;

    // ws layout (u16 units). po overlays xt (xt dead once proj completes).
    u16* vvp  = (u16*)d_ws;                          // B*C*L      (8 MB)
    u16* qtp  = vvp + (size_t)B * C * L;             // B*L*CQK    (1 MB)
    u16* ktp  = qtp + (size_t)B * L * CQK;           // B*L*CQK    (1 MB)
    u16* Wall = ktp + (size_t)B * L * CQK;           // 320*256    (160 KB)
    float* ball = (float*)(Wall + 320 * 256);        // 320 fp32
    u16* xt   = Wall + 320 * 256 + 640;              // B*L*C      (8 MB)
    u16* po   = xt;                                  // 32 MB partials
    float* plsum = (float*)(po + (size_t)B * 32 * SSEG * 2048 * 8);  // 64K fp32

    prep<<<1104, 256, 0, stream>>>(x, xt, Wq, bq, Wk, bk, Wv, bv, Wall, ball);
    proj<<<dim3(L / 32, B), 256, 0, stream>>>(xt, Wall, ball, qtp, ktp, vvp);
    attn<<<1024, 256, 0, stream>>>(qtp, ktp, vvp, po, plsum);
    combine<<<dim3(L / 64, B, SSEG), 256, 0, stream>>>(po, plsum, x, gm, out);
}